// Round 10
// baseline (26.699 us; speedup 1.0000x reference)
//
#include <hip/hip_runtime.h>
#include <math.h>

#define NPTS   131072
#define MBOX   128
#define NBOX   256
#define NFPS   512

#define NTHR   1024
#define NWAVE  16
#define PPW    (NPTS / NWAVE)       // 8192 points per wave
#define NGRP   (PPW / 64)           // 128 ballot-groups per wave
#define DWPB   (NPTS / 32)          // 4096 bitmask dwords per box

// One block = one box; block streams ALL points once.
// Each 64-point group's ballot IS the bitmask dword-pair.
// Two 8-group register buffers give 16 outstanding loads/lane.
__global__ __launch_bounds__(NTHR)
void roi_one(const float* __restrict__ points,   // (N,4): [b,x,y,z]
             const float* __restrict__ boxes,    // (B,M,7)
             int* __restrict__ out_idx,          // (NBOX, 512)
             int* __restrict__ out_num)          // (NBOX)
{
    const int box  = blockIdx.x;                 // 0..255
    const int tid  = threadIdx.x;
    const int lane = tid & 63;
    const int w    = tid >> 6;

    __shared__ unsigned s_bits[DWPB];            // 16 KB, linear (b128-aligned)
    __shared__ int      s_wsum[NWAVE];

    // prologue: issue 16 groups of loads immediately
    const float4* p4 = (const float4*)points + w * PPW + lane;
    float4 b0[8], b1[8];
    #pragma unroll
    for (int u = 0; u < 8; ++u) b0[u] = p4[u * 64];
    #pragma unroll
    for (int u = 0; u < 8; ++u) b1[u] = p4[(8 + u) * 64];

    // box params PER-THREAD (wave-uniform, deterministic -> identical bits).
    // fp32/f64 ops verbatim from passing kernels; trig hides under the loads.
    const float* bx = boxes + box * 7;
    const float cx = bx[0], cy = bx[1], cz = bx[2];
    const float hx = __fmul_rn(__fadd_rn(bx[4], 2.0f), 0.5f);   // f(bdy)
    const float hy = __fmul_rn(__fadd_rn(bx[3], 2.0f), 0.5f);   // f(bdx)
    const float hz = __fmul_rn(__fadd_rn(bx[5], 2.0f), 0.5f);
    const float hp = -__fadd_rn(bx[6], 1.5707963705062866f);    // fl32(pi/2)
    const float c  = (float)cos((double)hp);
    const float s  = (float)sin((double)hp);
    const float bBf = (float)(box >> 7);         // batch as exact float 0/1

#define ROI_TEST(q, out) do {                                            \
        const float dx_ = __fsub_rn((q).y, cx);                          \
        const float dy_ = __fsub_rn((q).z, cy);                          \
        const float dz_ = __fsub_rn((q).w, cz);                          \
        const float lx_ = __fadd_rn(__fmul_rn(dx_, c), __fmul_rn(dy_, s)); \
        const float ly_ = __fadd_rn(__fmul_rn(-dx_, s), __fmul_rn(dy_, c)); \
        (out) = __ballot(((q).x == bBf) & (fabsf(lx_) <= hx) &           \
                         (fabsf(ly_) <= hy) & (fabsf(dz_) <= hz));       \
    } while (0)

    unsigned long long bal[8];
    #pragma unroll 1
    for (int jo = 0; jo < NGRP; jo += 16) {
        // ---- compute buffer 0 (groups jo..jo+7), refill it with jo+16.. ----
        #pragma unroll
        for (int u = 0; u < 8; ++u) ROI_TEST(b0[u], bal[u]);
        if (jo + 16 < NGRP) {
            #pragma unroll
            for (int u = 0; u < 8; ++u) b0[u] = p4[(jo + 16 + u) * 64];
        }
        if (lane == 0) {
            uint4* dst = (uint4*)&s_bits[w * (NGRP * 2) + jo * 2];
            #pragma unroll
            for (int u = 0; u < 4; ++u)
                dst[u] = make_uint4((unsigned)bal[2*u],
                                    (unsigned)(bal[2*u] >> 32),
                                    (unsigned)bal[2*u + 1],
                                    (unsigned)(bal[2*u + 1] >> 32));
        }
        // ---- compute buffer 1 (groups jo+8..jo+15), refill with jo+24.. ----
        #pragma unroll
        for (int u = 0; u < 8; ++u) ROI_TEST(b1[u], bal[u]);
        if (jo + 24 < NGRP) {
            #pragma unroll
            for (int u = 0; u < 8; ++u) b1[u] = p4[(jo + 24 + u) * 64];
        }
        if (lane == 0) {
            uint4* dst = (uint4*)&s_bits[w * (NGRP * 2) + (jo + 8) * 2];
            #pragma unroll
            for (int u = 0; u < 4; ++u)
                dst[u] = make_uint4((unsigned)bal[2*u],
                                    (unsigned)(bal[2*u] >> 32),
                                    (unsigned)bal[2*u + 1],
                                    (unsigned)(bal[2*u + 1] >> 32));
        }
    }
    __syncthreads();

    // ---- ordered compaction: thread t owns dwords [4t,4t+4) = points [128t,128t+128)
    const uint4 qv = ((const uint4*)s_bits)[tid];     // conflict-free b128
    unsigned v[4] = {qv.x, qv.y, qv.z, qv.w};
    int cnt = __popc(v[0]) + __popc(v[1]) + __popc(v[2]) + __popc(v[3]);

    int incl = cnt;
    #pragma unroll
    for (int off = 1; off < 64; off <<= 1) {
        const int x = __shfl_up(incl, off, 64);
        if (lane >= off) incl += x;
    }
    if (lane == 63) s_wsum[w] = incl;
    __syncthreads();

    int wpre = 0, total = 0;
    #pragma unroll
    for (int ww = 0; ww < NWAVE; ++ww) {
        const int x = s_wsum[ww];
        if (ww < w) wpre += x;
        total += x;
    }
    int pos = wpre + (incl - cnt);
    const int pn = total < NFPS ? total : NFPS;

    const int obase = box * NFPS;
    if (tid < NFPS && tid >= pn) out_idx[obase + tid] = 0;   // zero tail

    const int pt0 = tid * 128;
    #pragma unroll
    for (int i = 0; i < 4; ++i) {
        unsigned x = v[i];
        while (x) {
            const int bpos = __ffs(x) - 1;
            if (pos < NFPS) out_idx[obase + pos] = pt0 + i * 32 + bpos;
            ++pos;
            x &= x - 1;
        }
    }
    if (tid == 0) out_num[box] = pn;
}

extern "C" void kernel_launch(void* const* d_in, const int* in_sizes, int n_in,
                              void* d_out, int out_size, void* d_ws, size_t ws_size,
                              hipStream_t stream) {
    const float* points = (const float*)d_in[0];   // (N,4) f32
    const float* boxes  = (const float*)d_in[1];   // (B,M,7) f32
    int* out_idx = (int*)d_out;                    // (B,M,512)
    int* out_num = (int*)d_out + NBOX * NFPS;      // (B,M)

    roi_one<<<NBOX, NTHR, 0, stream>>>(points, boxes, out_idx, out_num);
}